// Round 7
// baseline (330.400 us; speedup 1.0000x reference)
//
#include <hip/hip_runtime.h>
#include <stdint.h>

#define NC 12
#define NHW (256*256)

typedef __attribute__((ext_vector_type(8))) short bf16x8;
typedef __attribute__((ext_vector_type(4))) float f32x4;
typedef __attribute__((ext_vector_type(4))) uint32_t u32x4;

// pack two f32 -> u32 of 2 bf16 (RNE); compiler fuses pairs to v_cvt_pk_bf16_f32
__device__ __forceinline__ uint32_t pkbf(float lo, float hi) {
    const uint16_t lu = __builtin_bit_cast(uint16_t, (__bf16)lo);
    const uint16_t hu = __builtin_bit_cast(uint16_t, (__bf16)hi);
    return (uint32_t)lu | ((uint32_t)hu << 16);
}

// Opaque-asm pin: value becomes un-rematerializable -> stays register-resident.
#define PIN(v) asm volatile("" : "+v"(v))

// unaligned-by-4 float4 load (clang emits one global_load_dwordx4; gfx950
// global supports 4B-aligned dwordx4)
__device__ __forceinline__ f32x4 ld4u(const float* pp) {
    f32x4 v; __builtin_memcpy(&v, pp, 16); return v;
}

// Fused NCA step, horizontal sweep + in-wave software pipeline.
// K-bijections (same on A and B => contraction exact):
//   GEMM1 (w1[96x48]·yT): slot(s,g,j): s=0 -> col 12g+j ; s=1,j<4 -> col 12g+8+j
//   GEMM2 (w2[12x96]·hT): slot(s2,g,j) -> col 32s2 + 16*(j>=4) + 4g + (j&3)
// GEMM1's D regs ARE GEMM2's B-frags: no LDS, no cross-lane exchange.
// Tap loads: one dwordx4 per (ch,row) covers the 3 horizontal taps; the next
// grp's 9 loads are issued BEFORE this grp's compute (ping-pong A/B buffers),
// so load latency hides under stencil+GEMM+pack (~1300 cy).
__global__ __launch_bounds__(256, 3) void nca_fused6(
    const float* __restrict__ x, const float* __restrict__ w1,
    const float* __restrict__ b1, const float* __restrict__ w2,
    const float* __restrict__ rmask, float* __restrict__ out)
{
    const int tid  = threadIdx.x;
    const int lane = tid & 63;
    const int wv   = tid >> 6;
    const int g    = lane >> 4;   // 16-lane group
    const int p    = lane & 15;   // pixel col (B/D), weight row (A)
    const int c0   = 3 * g;       // this lane's first perception channel

    // ---- one-time weight fragments, pinned resident ----
    u32x4 a1u[6][2];
    f32x4 biasv[6];
    #pragma unroll
    for (int t = 0; t < 6; ++t) {
        const int row = 16*t + p;
        const float4 fa = *reinterpret_cast<const float4*>(w1 + row*48 + 12*g + 0);
        const float4 fb = *reinterpret_cast<const float4*>(w1 + row*48 + 12*g + 4);
        const float4 fc = *reinterpret_cast<const float4*>(w1 + row*48 + 12*g + 8);
        a1u[t][0] = (u32x4){ pkbf(fa.x, fa.y), pkbf(fa.z, fa.w), pkbf(fb.x, fb.y), pkbf(fb.z, fb.w) };
        a1u[t][1] = (u32x4){ pkbf(fc.x, fc.y), pkbf(fc.z, fc.w), 0u, 0u };
        biasv[t] = *reinterpret_cast<const f32x4*>(b1 + 16*t + 4*g);
        PIN(a1u[t][0]); PIN(a1u[t][1]); PIN(biasv[t]);
    }
    u32x4 a2u[3];
    #pragma unroll
    for (int s = 0; s < 3; ++s) {
        u32x4 u = {0u, 0u, 0u, 0u};
        if (p < NC) {
            const float4 wa = *reinterpret_cast<const float4*>(w2 + p*96 + 32*s + 4*g);
            const float4 wb = *reinterpret_cast<const float4*>(w2 + p*96 + 32*s + 16 + 4*g);
            u = (u32x4){ pkbf(wa.x, wa.y), pkbf(wa.z, wa.w), pkbf(wb.x, wb.y), pkbf(wb.z, wb.w) };
        }
        a2u[s] = u;
        PIN(a2u[s]);
    }

    // grid: 2048 blocks = 32 batches x 64 four-row strips; wave owns one row
    const int b  = blockIdx.x >> 6;
    const int h  = (blockIdx.x & 63) * 4 + wv;
    const float* __restrict__ xb = x + (size_t)b * NC * NHW;
    const float* __restrict__ mb = rmask + (size_t)b * NHW;
    float* __restrict__ ob = out + (size_t)b * NC * NHW;

    const int hm = (h - 1) & 255;
    const int hp = (h + 1) & 255;
    const int hrow = h << 8;
    int rb[9];      // tap-row element offsets (3 ch x 3 rows)
    #pragma unroll
    for (int ci = 0; ci < 3; ++ci) {
        const int cb = (c0 + ci) * NHW;
        rb[3*ci+0] = cb + (hm << 8);
        rb[3*ci+1] = cb + hrow;
        rb[3*ci+2] = cb + (hp << 8);
    }
    int voff[9];    // per-lane 32-bit offsets for the vector tap loads (at wc-1)
    #pragma unroll
    for (int q = 0; q < 9; ++q) voff[q] = rb[q] + p - 1;

    // ---- compute core: taps v0..v8 per channel already in registers ----
    auto core = [&](const int wc, const float (&tv)[3][9]) {
        uint32_t yw[6];
        #pragma unroll
        for (int ci = 0; ci < 3; ++ci) {
            const float v0 = tv[ci][0], v1 = tv[ci][1], v2 = tv[ci][2];
            const float v3 = tv[ci][3], v4 = tv[ci][4], v5 = tv[ci][5];
            const float v6 = tv[ci][6], v7 = tv[ci][7], v8 = tv[ci][8];
            const float fsx = (v2 - v0) + 2.f*(v5 - v3) + (v8 - v6);
            const float fsy = (v6 - v0) + 2.f*(v7 - v1) + (v8 - v2);
            const float flp = ((v0 + v2) + (v6 + v8)) + 2.f*((v1 + v3) + (v5 + v7)) - 12.f*v4;
            yw[2*ci]   = pkbf(v4, fsx);   // ident, sobel_x
            yw[2*ci+1] = pkbf(fsy, flp);  // sobel_xT, lap
        }
        const bf16x8 yf0 = __builtin_bit_cast(bf16x8, (u32x4){yw[0], yw[1], yw[2], yw[3]});
        const bf16x8 yf1 = __builtin_bit_cast(bf16x8, (u32x4){yw[4], yw[5], 0u, 0u});

        uint32_t pu[6][2];
        #pragma unroll
        for (int t = 0; t < 6; ++t) {
            f32x4 acc = biasv[t];
            acc = __builtin_amdgcn_mfma_f32_16x16x32_bf16(__builtin_bit_cast(bf16x8, a1u[t][0]), yf0, acc, 0, 0, 0);
            acc = __builtin_amdgcn_mfma_f32_16x16x32_bf16(__builtin_bit_cast(bf16x8, a1u[t][1]), yf1, acc, 0, 0, 0);
            pu[t][0] = pkbf(fmaxf(acc[0], 0.f), fmaxf(acc[1], 0.f));
            pu[t][1] = pkbf(fmaxf(acc[2], 0.f), fmaxf(acc[3], 0.f));
        }

        f32x4 acc2 = {0.f, 0.f, 0.f, 0.f};
        #pragma unroll
        for (int s2 = 0; s2 < 3; ++s2) {
            const u32x4 fb2 = { pu[2*s2][0], pu[2*s2][1], pu[2*s2+1][0], pu[2*s2+1][1] };
            acc2 = __builtin_amdgcn_mfma_f32_16x16x32_bf16(__builtin_bit_cast(bf16x8, a2u[s2]), __builtin_bit_cast(bf16x8, fb2), acc2, 0, 0, 0);
        }

        const float um = floorf(mb[hrow + wc] + 0.5f);
        if (g < 3) {
            #pragma unroll
            for (int r = 0; r < 4; ++r) {
                const int idx = (4*g + r) * NHW + hrow + wc;
                ob[idx] = xb[idx] + acc2[r] * um;
            }
        }
    };

    // vector-path body: taps come from the prefetched float4s
    auto corev = [&](const int wc, const f32x4* CUR) {
        float tv[3][9];
        #pragma unroll
        for (int ci = 0; ci < 3; ++ci)
            #pragma unroll
            for (int r = 0; r < 3; ++r) {
                tv[ci][3*r+0] = CUR[3*ci+r].x;
                tv[ci][3*r+1] = CUR[3*ci+r].y;
                tv[ci][3*r+2] = CUR[3*ci+r].z;
            }
        core(wc, tv);
    };
    // scalar-path body (wrap groups 0 and 15)
    auto cores = [&](const int wc, const int dm, const int dp) {
        float tv[3][9];
        #pragma unroll
        for (int ci = 0; ci < 3; ++ci)
            #pragma unroll
            for (int r = 0; r < 3; ++r) {
                const float* rp = xb + rb[3*ci+r] + wc;
                tv[ci][3*r+0] = rp[dm];
                tv[ci][3*r+1] = rp[0];
                tv[ci][3*r+2] = rp[dp];
            }
        core(wc, tv);
    };

    f32x4 A[9], B[9];

    // prologue: issue grp1's loads, then do grp0 (wrap) under their latency
    #pragma unroll
    for (int q = 0; q < 9; ++q) A[q] = ld4u(xb + voff[q] + 16);
    cores(p, (p == 0) ? 255 : -1, 1);

    // grps 1..14, ping-pong: prefetch grp+1 before computing grp
    #pragma unroll 1
    for (int gp = 0; gp < 7; ++gp) {
        const int g1 = 1 + 2*gp;
        #pragma unroll
        for (int q = 0; q < 9; ++q) B[q] = ld4u(xb + voff[q] + ((g1 + 1) << 4));
        corev((g1 << 4) + p, A);
        if (g1 + 2 < 15) {
            #pragma unroll
            for (int q = 0; q < 9; ++q) A[q] = ld4u(xb + voff[q] + ((g1 + 2) << 4));
        }
        corev(((g1 + 1) << 4) + p, B);
    }

    // grp 15 (wrap) via scalar path — avoids float4 overhang past the buffer
    cores(240 + p, -1, (p == 15) ? -255 : 1);
}

extern "C" void kernel_launch(void* const* d_in, const int* in_sizes, int n_in,
                              void* d_out, int out_size, void* d_ws, size_t ws_size,
                              hipStream_t stream) {
    const float* x  = (const float*)d_in[0];
    const float* w1 = (const float*)d_in[1];
    const float* b1 = (const float*)d_in[2];
    const float* w2 = (const float*)d_in[3];
    const float* rm = (const float*)d_in[4];
    float* out = (float*)d_out;
    nca_fused6<<<dim3(32 * 64), dim3(256), 0, stream>>>(x, w1, b1, w2, rm, out);
}

// Round 8
// 153.302 us; speedup vs baseline: 2.1552x; 2.1552x over previous
//
#include <hip/hip_runtime.h>
#include <stdint.h>

#define NC 12
#define NHW (256*256)

typedef __attribute__((ext_vector_type(8))) short bf16x8;
typedef __attribute__((ext_vector_type(4))) float f32x4;
typedef __attribute__((ext_vector_type(4))) uint32_t u32x4;

// pack two f32 -> u32 of 2 bf16 (RNE); compiler fuses pairs to v_cvt_pk_bf16_f32
__device__ __forceinline__ uint32_t pkbf(float lo, float hi) {
    const uint16_t lu = __builtin_bit_cast(uint16_t, (__bf16)lo);
    const uint16_t hu = __builtin_bit_cast(uint16_t, (__bf16)hi);
    return (uint32_t)lu | ((uint32_t)hu << 16);
}

// Opaque-asm pin: value becomes un-rematerializable -> stays register-resident.
#define PIN(v) asm volatile("" : "+v"(v))

// Fused NCA step. Horizontal sweep (r5: vertical walk = 4.8x FETCH, never again);
// NO pointer-passed register arrays (r7: scratch spill = 7x FETCH, never again).
// K-bijections (same on A and B => contraction exact):
//   GEMM1 (w1[96x48]·yT): slot(s,g,j): s=0 -> col 12g+j ; s=1,j<4 -> col 12g+8+j
//   GEMM2 (w2[12x96]·hT): slot(s2,g,j) -> col 32s2 + 16*(j>=4) + 4g + (j&3)
// GEMM1's D regs ARE GEMM2's B-frags: no LDS, no cross-lane exchange.
// NEW vs r6: each wave owns TWO adjacent rows -> one 36-load tap block
// (4 rows x 3ch x 3 taps) feeds two independent compute chains (1.5x fewer
// loads, 2 chains for the scheduler); grp loop unrolled 2x so the next
// iteration's loads issue under this iteration's ~1400cy of compute.
__global__ __launch_bounds__(64) void nca_fused7(
    const float* __restrict__ x, const float* __restrict__ w1,
    const float* __restrict__ b1, const float* __restrict__ w2,
    const float* __restrict__ rmask, float* __restrict__ out)
{
    const int lane = threadIdx.x & 63;
    const int g    = lane >> 4;   // 16-lane group
    const int p    = lane & 15;   // pixel col (B/D), weight row (A)
    const int c0   = 3 * g;       // this lane's first perception channel

    // ---- one-time weight fragments, pinned resident ----
    u32x4 a1u[6][2];
    f32x4 biasv[6];
    #pragma unroll
    for (int t = 0; t < 6; ++t) {
        const int row = 16*t + p;
        const float4 fa = *reinterpret_cast<const float4*>(w1 + row*48 + 12*g + 0);
        const float4 fb = *reinterpret_cast<const float4*>(w1 + row*48 + 12*g + 4);
        const float4 fc = *reinterpret_cast<const float4*>(w1 + row*48 + 12*g + 8);
        a1u[t][0] = (u32x4){ pkbf(fa.x, fa.y), pkbf(fa.z, fa.w), pkbf(fb.x, fb.y), pkbf(fb.z, fb.w) };
        a1u[t][1] = (u32x4){ pkbf(fc.x, fc.y), pkbf(fc.z, fc.w), 0u, 0u };
        biasv[t] = *reinterpret_cast<const f32x4*>(b1 + 16*t + 4*g);
        PIN(a1u[t][0]); PIN(a1u[t][1]); PIN(biasv[t]);
    }
    u32x4 a2u[3];
    #pragma unroll
    for (int s = 0; s < 3; ++s) {
        u32x4 u = {0u, 0u, 0u, 0u};
        if (p < NC) {
            const float4 wa = *reinterpret_cast<const float4*>(w2 + p*96 + 32*s + 4*g);
            const float4 wb = *reinterpret_cast<const float4*>(w2 + p*96 + 32*s + 16 + 4*g);
            u = (u32x4){ pkbf(wa.x, wa.y), pkbf(wa.z, wa.w), pkbf(wb.x, wb.y), pkbf(wb.z, wb.w) };
        }
        a2u[s] = u;
        PIN(a2u[s]);
    }

    // grid: 4096 one-wave blocks = 32 batches x 128 row-pairs
    const int b  = blockIdx.x >> 7;
    const int ra = (blockIdx.x & 127) * 2;      // wave computes rows ra, ra+1
    const float* __restrict__ xb = x + (size_t)b * NC * NHW;
    const float* __restrict__ mb = rmask + (size_t)b * NHW;
    float* __restrict__ ob = out + (size_t)b * NC * NHW;

    // tap rows ra-1 .. ra+2 (wrap only possible on first/last pair)
    const int rows[4] = { (ra + 255) & 255, ra, ra + 1, (ra + 2) & 255 };
    int rq[3][4];   // element base of [ch][tap-row]
    #pragma unroll
    for (int ci = 0; ci < 3; ++ci)
        #pragma unroll
        for (int q = 0; q < 4; ++q)
            rq[ci][q] = (c0 + ci) * NHW + (rows[q] << 8);
    const int hr0 = ra << 8;
    const int hr1 = hr0 + 256;

    // ---- compute one output row from tap rows qo..qo+2 (qo const after inline) ----
    auto core = [&](const int wc, const int hrow, const float (&t)[3][4][3], const int qo) {
        uint32_t yw[6];
        #pragma unroll
        for (int ci = 0; ci < 3; ++ci) {
            const float v0 = t[ci][qo+0][0], v1 = t[ci][qo+0][1], v2 = t[ci][qo+0][2];
            const float v3 = t[ci][qo+1][0], v4 = t[ci][qo+1][1], v5 = t[ci][qo+1][2];
            const float v6 = t[ci][qo+2][0], v7 = t[ci][qo+2][1], v8 = t[ci][qo+2][2];
            const float fsx = (v2 - v0) + 2.f*(v5 - v3) + (v8 - v6);
            const float fsy = (v6 - v0) + 2.f*(v7 - v1) + (v8 - v2);
            const float flp = ((v0 + v2) + (v6 + v8)) + 2.f*((v1 + v3) + (v5 + v7)) - 12.f*v4;
            yw[2*ci]   = pkbf(v4, fsx);   // ident, sobel_x
            yw[2*ci+1] = pkbf(fsy, flp);  // sobel_xT, lap
        }
        const bf16x8 yf0 = __builtin_bit_cast(bf16x8, (u32x4){yw[0], yw[1], yw[2], yw[3]});
        const bf16x8 yf1 = __builtin_bit_cast(bf16x8, (u32x4){yw[4], yw[5], 0u, 0u});

        uint32_t pu[6][2];
        #pragma unroll
        for (int t6 = 0; t6 < 6; ++t6) {
            f32x4 acc = biasv[t6];
            acc = __builtin_amdgcn_mfma_f32_16x16x32_bf16(__builtin_bit_cast(bf16x8, a1u[t6][0]), yf0, acc, 0, 0, 0);
            acc = __builtin_amdgcn_mfma_f32_16x16x32_bf16(__builtin_bit_cast(bf16x8, a1u[t6][1]), yf1, acc, 0, 0, 0);
            pu[t6][0] = pkbf(fmaxf(acc[0], 0.f), fmaxf(acc[1], 0.f));
            pu[t6][1] = pkbf(fmaxf(acc[2], 0.f), fmaxf(acc[3], 0.f));
        }

        f32x4 acc2 = {0.f, 0.f, 0.f, 0.f};
        #pragma unroll
        for (int s2 = 0; s2 < 3; ++s2) {
            const u32x4 fb2 = { pu[2*s2][0], pu[2*s2][1], pu[2*s2+1][0], pu[2*s2+1][1] };
            acc2 = __builtin_amdgcn_mfma_f32_16x16x32_bf16(__builtin_bit_cast(bf16x8, a2u[s2]), __builtin_bit_cast(bf16x8, fb2), acc2, 0, 0, 0);
        }

        const float um = floorf(mb[hrow + wc] + 0.5f);
        if (g < 3) {
            #pragma unroll
            for (int r = 0; r < 4; ++r) {
                const int idx = (4*g + r) * NHW + hrow + wc;
                ob[idx] = xb[idx] + acc2[r] * um;
            }
        }
    };

    // ---- double-row body: 36 tap loads feed two independent row chains ----
    auto dbody = [&](const int wc, const int dm, const int dp) {
        float t[3][4][3];   // [ch][tap-row][tap] — all const-indexed, SROA-safe
        #pragma unroll
        for (int ci = 0; ci < 3; ++ci)
            #pragma unroll
            for (int q = 0; q < 4; ++q) {
                const float* rp = xb + rq[ci][q] + wc;
                t[ci][q][0] = rp[dm];
                t[ci][q][1] = rp[0];
                t[ci][q][2] = rp[dp];
            }
        core(wc, hr0, t, 0);
        core(wc, hr1, t, 1);
    };

    dbody(p, (p == 0) ? 255 : -1, 1);          // grp 0: left wrap on lane p==0
    #pragma unroll 2
    for (int grp = 1; grp < 15; ++grp)
        dbody((grp << 4) + p, -1, 1);          // middle: immediate tap offsets
    dbody(240 + p, -1, (p == 15) ? -255 : 1);  // grp 15: right wrap on lane p==15
}

extern "C" void kernel_launch(void* const* d_in, const int* in_sizes, int n_in,
                              void* d_out, int out_size, void* d_ws, size_t ws_size,
                              hipStream_t stream) {
    const float* x  = (const float*)d_in[0];
    const float* w1 = (const float*)d_in[1];
    const float* b1 = (const float*)d_in[2];
    const float* w2 = (const float*)d_in[3];
    const float* rm = (const float*)d_in[4];
    float* out = (float*)d_out;
    nca_fused7<<<dim3(32 * 128), dim3(64), 0, stream>>>(x, w1, b1, w2, rm, out);
}

// Round 9
// 86.897 us; speedup vs baseline: 3.8022x; 1.7642x over previous
//
#include <hip/hip_runtime.h>
#include <stdint.h>

#define NC 12
#define NHW (256*256)
#define RSTR 136            // LDS floats per tap-row: [3]=halo-L, [4..131]=cols, [132]=halo-R
#define CSTR 840            // LDS floats per channel: 6*136=816 +24 pad so CSTR%32==8 (bank spread)

typedef __attribute__((ext_vector_type(8))) short bf16x8;
typedef __attribute__((ext_vector_type(4))) float f32x4;
typedef __attribute__((ext_vector_type(4))) uint32_t u32x4;
typedef __attribute__((ext_vector_type(2))) __bf16 bf16x2v;

// canonical 2-wide bf16 vector build -> v_cvt_pk_bf16_f32
__device__ __forceinline__ uint32_t pkbf(float lo, float hi) {
    bf16x2v v = { (__bf16)lo, (__bf16)hi };
    return __builtin_bit_cast(uint32_t, v);
}
// opaque pin: keeps weight fragments register-resident (r6: 140->119.7)
#define PIN(v) asm volatile("" : "+v"(v))

// Fused NCA step with LDS-staged input tile.
// Block: 4 output rows x 128 cols; stages 12ch x 6 tap-rows x 130 cols (f32,
// 40320B LDS) via coalesced float4 loads; wrap columns staged as halos so the
// compute loop has ZERO wrap branches. Taps + epilogue-x come from LDS.
// K-bijections (same on A and B => contraction exact):
//   GEMM1 (w1[96x48]·yT): slot(s,g,j): s=0 -> col 12g+j ; s=1,j<4 -> col 12g+8+j
//   GEMM2 (w2[12x96]·hT): slot(s2,g,j) -> col 32s2 + 16*(j>=4) + 4g + (j&3)
// GEMM1's D regs ARE GEMM2's B-frags: no exchange needed.
__global__ __launch_bounds__(256, 3) void nca_fused8(
    const float* __restrict__ x, const float* __restrict__ w1,
    const float* __restrict__ b1, const float* __restrict__ w2,
    const float* __restrict__ rmask, float* __restrict__ out)
{
    __shared__ float smem[12 * CSTR];   // 40320 B

    const int tid  = threadIdx.x;
    const int lane = tid & 63;
    const int wv   = tid >> 6;
    const int g    = lane >> 4;   // 16-lane group
    const int p    = lane & 15;   // pixel col (B/D), weight row (A)
    const int c0   = 3 * g;       // this lane's first perception channel

    // ---- resident weight fragments + bias, pinned ----
    u32x4 a1u[6][2];
    f32x4 biasv[6];
    #pragma unroll
    for (int t = 0; t < 6; ++t) {
        const int row = 16*t + p;
        const float4 fa = *reinterpret_cast<const float4*>(w1 + row*48 + 12*g + 0);
        const float4 fb = *reinterpret_cast<const float4*>(w1 + row*48 + 12*g + 4);
        const float4 fc = *reinterpret_cast<const float4*>(w1 + row*48 + 12*g + 8);
        a1u[t][0] = (u32x4){ pkbf(fa.x, fa.y), pkbf(fa.z, fa.w), pkbf(fb.x, fb.y), pkbf(fb.z, fb.w) };
        a1u[t][1] = (u32x4){ pkbf(fc.x, fc.y), pkbf(fc.z, fc.w), 0u, 0u };
        biasv[t] = *reinterpret_cast<const f32x4*>(b1 + 16*t + 4*g);
        PIN(a1u[t][0]); PIN(a1u[t][1]); PIN(biasv[t]);
    }
    u32x4 a2u[3];
    #pragma unroll
    for (int s = 0; s < 3; ++s) {
        u32x4 u = {0u, 0u, 0u, 0u};
        if (p < NC) {
            const float4 wa = *reinterpret_cast<const float4*>(w2 + p*96 + 32*s + 4*g);
            const float4 wb = *reinterpret_cast<const float4*>(w2 + p*96 + 32*s + 16 + 4*g);
            u = (u32x4){ pkbf(wa.x, wa.y), pkbf(wa.z, wa.w), pkbf(wb.x, wb.y), pkbf(wb.z, wb.w) };
        }
        a2u[s] = u;
        PIN(a2u[s]);
    }

    // grid: 4096 blocks = 32 batches x 64 row-strips x 2 col-halves
    const int b     = blockIdx.x >> 7;
    const int strip = (blockIdx.x >> 1) & 63;
    const int half  = blockIdx.x & 1;
    const int ra    = strip << 2;      // first output row
    const int c0g   = half << 7;       // first output col
    const float* __restrict__ xb = x + (size_t)b * NC * NHW;
    const float* __restrict__ mb = rmask + (size_t)b * NHW;
    float* __restrict__ ob = out + (size_t)b * NC * NHW;

    // ---- stage 12ch x 6 tap-rows x (128 + 2 halo) cols, f32 ----
    {
        const int q = tid >> 5;        // half-row slot 0..7
        const int l = tid & 31;        // 4-float chunk within half-row
        #pragma unroll
        for (int j = 0; j < 9; ++j) {
            const int hr  = 8*j + q;               // 0..71 = (ch, tap-row)
            const int c   = hr / 6;
            const int r   = hr - 6*c;
            const int row = (ra + 255 + r) & 255;  // tap-row r -> global row ra-1+r
            const f32x4 v = *reinterpret_cast<const f32x4*>(xb + c*NHW + (row << 8) + c0g + (l << 2));
            *reinterpret_cast<f32x4*>(&smem[c*CSTR + r*RSTR + 4 + (l << 2)]) = v;
        }
        if (tid < 144) {               // 72 (ch,row) pairs x 2 wrap-halo cols
            const int hr  = tid >> 1;
            const int side= tid & 1;
            const int c   = hr / 6;
            const int r   = hr - 6*c;
            const int row = (ra + 255 + r) & 255;
            const int col = side ? ((c0g + 128) & 255) : ((c0g + 255) & 255);
            smem[c*CSTR + r*RSTR + (side ? 132 : 3)] = xb[c*NHW + (row << 8) + col];
        }
    }
    __syncthreads();

    // wave wv owns output row ra+wv; its tap rows are slots wv, wv+1, wv+2
    const int h    = ra + wv;
    const int hrow = h << 8;

    #pragma unroll 2
    for (int grp = 0; grp < 8; ++grp) {
        const int wcl = (grp << 4) + p;        // local col 0..127
        const int wcg = c0g + wcl;             // global col

        // ---- perception from LDS (idx 3+wcl .. 5+wcl = cols wcl-1..wcl+1) ----
        uint32_t yw[6];
        #pragma unroll
        for (int ci = 0; ci < 3; ++ci) {
            const float* t0 = &smem[(c0 + ci)*CSTR + (wv + 0)*RSTR + 3 + wcl];
            const float* t1 = &smem[(c0 + ci)*CSTR + (wv + 1)*RSTR + 3 + wcl];
            const float* t2 = &smem[(c0 + ci)*CSTR + (wv + 2)*RSTR + 3 + wcl];
            const float v0 = t0[0], v1 = t0[1], v2 = t0[2];
            const float v3 = t1[0], v4 = t1[1], v5 = t1[2];
            const float v6 = t2[0], v7 = t2[1], v8 = t2[2];
            const float fsx = (v2 - v0) + 2.f*(v5 - v3) + (v8 - v6);
            const float fsy = (v6 - v0) + 2.f*(v7 - v1) + (v8 - v2);
            const float flp = ((v0 + v2) + (v6 + v8)) + 2.f*((v1 + v3) + (v5 + v7)) - 12.f*v4;
            yw[2*ci]   = pkbf(v4, fsx);   // ident, sobel_x
            yw[2*ci+1] = pkbf(fsy, flp);  // sobel_xT, lap
        }
        const bf16x8 yf0 = __builtin_bit_cast(bf16x8, (u32x4){yw[0], yw[1], yw[2], yw[3]});
        const bf16x8 yf1 = __builtin_bit_cast(bf16x8, (u32x4){yw[4], yw[5], 0u, 0u});

        // ---- GEMM1 (bias C-in, ReLU, pack) + GEMM2, MFMA cluster prioritized ----
        __builtin_amdgcn_s_setprio(1);
        uint32_t pu[6][2];
        #pragma unroll
        for (int t = 0; t < 6; ++t) {
            f32x4 acc = biasv[t];
            acc = __builtin_amdgcn_mfma_f32_16x16x32_bf16(__builtin_bit_cast(bf16x8, a1u[t][0]), yf0, acc, 0, 0, 0);
            acc = __builtin_amdgcn_mfma_f32_16x16x32_bf16(__builtin_bit_cast(bf16x8, a1u[t][1]), yf1, acc, 0, 0, 0);
            pu[t][0] = pkbf(fmaxf(acc[0], 0.f), fmaxf(acc[1], 0.f));
            pu[t][1] = pkbf(fmaxf(acc[2], 0.f), fmaxf(acc[3], 0.f));
        }
        f32x4 acc2 = {0.f, 0.f, 0.f, 0.f};
        #pragma unroll
        for (int s2 = 0; s2 < 3; ++s2) {
            const u32x4 fb2 = { pu[2*s2][0], pu[2*s2][1], pu[2*s2+1][0], pu[2*s2+1][1] };
            acc2 = __builtin_amdgcn_mfma_f32_16x16x32_bf16(__builtin_bit_cast(bf16x8, a2u[s2]), __builtin_bit_cast(bf16x8, fb2), acc2, 0, 0, 0);
        }
        __builtin_amdgcn_s_setprio(0);

        // ---- epilogue: x from LDS, out = x + upd * floor(rand + 0.5) ----
        const float um = floorf(mb[hrow + wcg] + 0.5f);
        if (g < 3) {
            #pragma unroll
            for (int r = 0; r < 4; ++r) {
                const float xv = smem[(4*g + r)*CSTR + (wv + 1)*RSTR + 4 + wcl];
                ob[(4*g + r)*NHW + hrow + wcg] = xv + acc2[r] * um;
            }
        }
    }
}

extern "C" void kernel_launch(void* const* d_in, const int* in_sizes, int n_in,
                              void* d_out, int out_size, void* d_ws, size_t ws_size,
                              hipStream_t stream) {
    const float* x  = (const float*)d_in[0];
    const float* w1 = (const float*)d_in[1];
    const float* b1 = (const float*)d_in[2];
    const float* w2 = (const float*)d_in[3];
    const float* rm = (const float*)d_in[4];
    float* out = (float*)d_out;
    nca_fused8<<<dim3(32 * 64 * 2), dim3(256), 0, stream>>>(x, w1, b1, w2, rm, out);
}

// Round 10
// 86.291 us; speedup vs baseline: 3.8289x; 1.0070x over previous
//
#include <hip/hip_runtime.h>
#include <stdint.h>

#define NC 12
#define NHW (256*256)
#define RSTR 136            // LDS floats per tap-row: [3]=halo-L, [4..131]=cols, [132]=halo-R
#define CSTR 840            // LDS floats per channel: 6*136=816 +24 pad, CSTR%32==8 (tap reads 2-way=free)

typedef __attribute__((ext_vector_type(8))) short bf16x8;
typedef __attribute__((ext_vector_type(4))) float f32x4;
typedef __attribute__((ext_vector_type(4))) uint32_t u32x4;
typedef __attribute__((ext_vector_type(2))) __bf16 bf16x2v;

// canonical 2-wide bf16 vector build -> v_cvt_pk_bf16_f32
__device__ __forceinline__ uint32_t pkbf(float lo, float hi) {
    bf16x2v v = { (__bf16)lo, (__bf16)hi };
    return __builtin_bit_cast(uint32_t, v);
}
// opaque pin: keeps weight fragments register-resident
#define PIN(v) asm volatile("" : "+v"(v))

// Fused NCA step, LDS-staged tile (r9) + three fixes:
//  (a) 4 blocks/CU (LDS 40448*4 = 161792 <= 160KiB),
//  (b) M-permuted GEMM2: D-row 4g+r holds out-channel 4r+((g+r)&3)  -> epilogue
//      LDS reads exactly 2-way (free), all 64 lanes store (no g<3 divergence),
//  (c) grp loop fully unrolled, all LDS/global addresses hoisted to base+imm.
// K-bijections (same on A and B => contraction exact):
//   GEMM1 (w1[96x48]·yT): slot(s,g,j): s=0 -> col 12g+j ; s=1,j<4 -> col 12g+8+j
//   GEMM2 (w2[12x96]·hT): slot(s2,g,j) -> col 32s2 + 16*(j>=4) + 4g + (j&3)
// GEMM1's D regs ARE GEMM2's B-frags: no exchange.
__global__ __launch_bounds__(256, 4) void nca_fused9(
    const float* __restrict__ x, const float* __restrict__ w1,
    const float* __restrict__ b1, const float* __restrict__ w2,
    const float* __restrict__ rmask, float* __restrict__ out)
{
    __shared__ float smem[12 * CSTR];   // 40320 B

    const int tid  = threadIdx.x;
    const int lane = tid & 63;
    const int wv   = tid >> 6;
    const int g    = lane >> 4;   // 16-lane group
    const int p    = lane & 15;   // pixel col (B/D), weight row (A)
    const int c0   = 3 * g;       // this lane's first perception channel

    // ---- resident weight fragments + bias, pinned ----
    u32x4 a1u[6][2];
    f32x4 biasv[6];
    #pragma unroll
    for (int t = 0; t < 6; ++t) {
        const int row = 16*t + p;
        const float4 fa = *reinterpret_cast<const float4*>(w1 + row*48 + 12*g + 0);
        const float4 fb = *reinterpret_cast<const float4*>(w1 + row*48 + 12*g + 4);
        const float4 fc = *reinterpret_cast<const float4*>(w1 + row*48 + 12*g + 8);
        a1u[t][0] = (u32x4){ pkbf(fa.x, fa.y), pkbf(fa.z, fa.w), pkbf(fb.x, fb.y), pkbf(fb.z, fb.w) };
        a1u[t][1] = (u32x4){ pkbf(fc.x, fc.y), pkbf(fc.z, fc.w), 0u, 0u };
        biasv[t] = *reinterpret_cast<const f32x4*>(b1 + 16*t + 4*g);
        PIN(a1u[t][0]); PIN(a1u[t][1]); PIN(biasv[t]);
    }
    // GEMM2 A with M-permutation: A-row m holds w2 row 4*(m&3)+(((m>>2)+(m&3))&3)
    u32x4 a2u[3];
    {
        const int rp = p & 3, gp = p >> 2;
        const int chA = 4*rp + ((gp + rp) & 3);
        #pragma unroll
        for (int s = 0; s < 3; ++s) {
            u32x4 u = {0u, 0u, 0u, 0u};
            if (rp < 3) {
                const float4 wa = *reinterpret_cast<const float4*>(w2 + chA*96 + 32*s + 4*g);
                const float4 wb = *reinterpret_cast<const float4*>(w2 + chA*96 + 32*s + 16 + 4*g);
                u = (u32x4){ pkbf(wa.x, wa.y), pkbf(wa.z, wa.w), pkbf(wb.x, wb.y), pkbf(wb.z, wb.w) };
            }
            a2u[s] = u;
            PIN(a2u[s]);
        }
    }

    // grid: 4096 blocks = 32 batches x 64 row-strips x 2 col-halves
    const int b     = blockIdx.x >> 7;
    const int strip = (blockIdx.x >> 1) & 63;
    const int half  = blockIdx.x & 1;
    const int ra    = strip << 2;      // first output row
    const int c0g   = half << 7;       // first output col
    const float* __restrict__ xb = x + (size_t)b * NC * NHW;
    const float* __restrict__ mb = rmask + (size_t)b * NHW;
    float* __restrict__ ob = out + (size_t)b * NC * NHW;

    // ---- stage 12ch x 6 tap-rows x (128 + 2 halo) cols, f32 ----
    {
        const int q = tid >> 5;        // half-row slot 0..7
        const int l = tid & 31;        // 4-float chunk within half-row
        #pragma unroll
        for (int j = 0; j < 9; ++j) {
            const int hr  = 8*j + q;               // 0..71 = (ch, tap-row)
            const int c   = hr / 6;
            const int r   = hr - 6*c;
            const int row = (ra + 255 + r) & 255;  // tap-row r -> global row ra-1+r
            const f32x4 v = *reinterpret_cast<const f32x4*>(xb + c*NHW + (row << 8) + c0g + (l << 2));
            *reinterpret_cast<f32x4*>(&smem[c*CSTR + r*RSTR + 4 + (l << 2)]) = v;
        }
        if (tid < 144) {               // 72 (ch,row) pairs x 2 wrap-halo cols
            const int hr  = tid >> 1;
            const int side= tid & 1;
            const int c   = hr / 6;
            const int r   = hr - 6*c;
            const int row = (ra + 255 + r) & 255;
            const int col = side ? ((c0g + 128) & 255) : ((c0g + 255) & 255);
            smem[c*CSTR + r*RSTR + (side ? 132 : 3)] = xb[c*NHW + (row << 8) + col];
        }
    }
    __syncthreads();

    // wave wv owns output row ra+wv; tap rows are slots wv, wv+1, wv+2
    const int h    = ra + wv;
    const int hrow = h << 8;

    // ---- hoisted bases: inner loop uses ONLY immediate offsets ----
    const float* tp[3][3];
    #pragma unroll
    for (int ci = 0; ci < 3; ++ci)
        #pragma unroll
        for (int q = 0; q < 3; ++q)
            tp[ci][q] = &smem[(c0 + ci)*CSTR + (wv + q)*RSTR + 3 + p];
    const float* xepi[3];
    float*       obp[3];
    #pragma unroll
    for (int r = 0; r < 3; ++r) {
        const int ch = 4*r + ((g + r) & 3);        // channel held in acc2[r]
        xepi[r] = &smem[ch*CSTR + (wv + 1)*RSTR + 4 + p];
        obp[r]  = ob + ch*NHW + hrow + c0g + p;
    }
    const float* mbp = mb + hrow + c0g + p;

    #pragma unroll
    for (int grp = 0; grp < 8; ++grp) {
        const int o = grp << 4;   // compile-time: all accesses below are base+imm

        // ---- perception from LDS (taps o..o+2 per (ch,row)) ----
        uint32_t yw[6];
        #pragma unroll
        for (int ci = 0; ci < 3; ++ci) {
            const float v0 = tp[ci][0][o+0], v1 = tp[ci][0][o+1], v2 = tp[ci][0][o+2];
            const float v3 = tp[ci][1][o+0], v4 = tp[ci][1][o+1], v5 = tp[ci][1][o+2];
            const float v6 = tp[ci][2][o+0], v7 = tp[ci][2][o+1], v8 = tp[ci][2][o+2];
            const float fsx = (v2 - v0) + 2.f*(v5 - v3) + (v8 - v6);
            const float fsy = (v6 - v0) + 2.f*(v7 - v1) + (v8 - v2);
            const float flp = ((v0 + v2) + (v6 + v8)) + 2.f*((v1 + v3) + (v5 + v7)) - 12.f*v4;
            yw[2*ci]   = pkbf(v4, fsx);   // ident, sobel_x
            yw[2*ci+1] = pkbf(fsy, flp);  // sobel_xT, lap
        }
        const bf16x8 yf0 = __builtin_bit_cast(bf16x8, (u32x4){yw[0], yw[1], yw[2], yw[3]});
        const bf16x8 yf1 = __builtin_bit_cast(bf16x8, (u32x4){yw[4], yw[5], 0u, 0u});

        // ---- GEMM1 (bias C-in, ReLU, pack) + GEMM2, MFMA cluster prioritized ----
        __builtin_amdgcn_s_setprio(1);
        uint32_t pu[6][2];
        #pragma unroll
        for (int t = 0; t < 6; ++t) {
            f32x4 acc = biasv[t];
            acc = __builtin_amdgcn_mfma_f32_16x16x32_bf16(__builtin_bit_cast(bf16x8, a1u[t][0]), yf0, acc, 0, 0, 0);
            acc = __builtin_amdgcn_mfma_f32_16x16x32_bf16(__builtin_bit_cast(bf16x8, a1u[t][1]), yf1, acc, 0, 0, 0);
            pu[t][0] = pkbf(fmaxf(acc[0], 0.f), fmaxf(acc[1], 0.f));
            pu[t][1] = pkbf(fmaxf(acc[2], 0.f), fmaxf(acc[3], 0.f));
        }
        f32x4 acc2 = {0.f, 0.f, 0.f, 0.f};
        #pragma unroll
        for (int s2 = 0; s2 < 3; ++s2) {
            const u32x4 fb2 = { pu[2*s2][0], pu[2*s2][1], pu[2*s2+1][0], pu[2*s2+1][1] };
            acc2 = __builtin_amdgcn_mfma_f32_16x16x32_bf16(__builtin_bit_cast(bf16x8, a2u[s2]), __builtin_bit_cast(bf16x8, fb2), acc2, 0, 0, 0);
        }
        __builtin_amdgcn_s_setprio(0);

        // ---- epilogue: all 64 lanes, 3 channels each, LDS reads 2-way (free) ----
        const float um = floorf(mbp[o] + 0.5f);
        #pragma unroll
        for (int r = 0; r < 3; ++r)
            obp[r][o] = xepi[r][o] + acc2[r] * um;
    }
}

extern "C" void kernel_launch(void* const* d_in, const int* in_sizes, int n_in,
                              void* d_out, int out_size, void* d_ws, size_t ws_size,
                              hipStream_t stream) {
    const float* x  = (const float*)d_in[0];
    const float* w1 = (const float*)d_in[1];
    const float* b1 = (const float*)d_in[2];
    const float* w2 = (const float*)d_in[3];
    const float* rm = (const float*)d_in[4];
    float* out = (float*)d_out;
    nca_fused9<<<dim3(32 * 64 * 2), dim3(256), 0, stream>>>(x, w1, b1, w2, rm, out);
}